// Round 9
// baseline (6510.930 us; speedup 1.0000x reference)
//
#include <hip/hip_runtime.h>

#define SS 4096
#define LL 16
#define HD 512
#define ECD 128
#define HHD 256

typedef __attribute__((ext_vector_type(8))) short short8;
typedef __attribute__((ext_vector_type(4))) float float4v;

__device__ __forceinline__ float bf2f(unsigned short u){
  union { unsigned int i; float f; } v; v.i = ((unsigned int)u) << 16; return v.f;
}
__device__ __forceinline__ unsigned short f2bf(float f){
  union { float f; unsigned int i; } v; v.f = f;
  unsigned int u = v.i;
  unsigned int r = (u + 0x7fffu + ((u >> 16) & 1u)) >> 16;
  return (unsigned short)r;
}
__device__ __forceinline__ float sigf(float x){ return 1.f / (1.f + __expf(-x)); }
__device__ __forceinline__ float tanh_f(float x){
  float e = __expf(2.f * x);
  return 1.f - 2.f / (e + 1.f);
}
__device__ __forceinline__ bool badf(float x){ return !(fabsf(x) < 1e30f); }

// int8 dot4: a,b are 4 packed signed int8; returns c + sum(a_i*b_i)
__device__ __forceinline__ int dot4i8(unsigned int a, unsigned int b, int c){
#if __has_builtin(__builtin_amdgcn_sdot4)
  return __builtin_amdgcn_sdot4((int)a, (int)b, c, false);
#else
  int s = c;
  s += (int)(char)(a)       * (int)(char)(b);
  s += (int)(char)(a >> 8)  * (int)(char)(b >> 8);
  s += (int)(char)(a >> 16) * (int)(char)(b >> 16);
  s += (int)(char)(a >> 24) * (int)(char)(b >> 24);
  return s;
#endif
}

// pack 8 f32 -> 8 bf16 (as int4) for LDS staging
__device__ __forceinline__ int4 cvt8(const float* __restrict__ s){
  union { unsigned short u[8]; int4 v; } pk;
#pragma unroll
  for (int i = 0; i < 8; ++i) pk.u[i] = f2bf(s[i]);
  return pk.v;
}

// ---------------- prep: xUb[c][n] = char_emb[c].Wih_c[n] + bih_c[n] + bhh_c[n]  (bf16 out)
__global__ void prep_xu_k(const float* __restrict__ char_emb,
                          const float* __restrict__ Wih_c,
                          const float* __restrict__ bih_c,
                          const float* __restrict__ bhh_c,
                          unsigned short* __restrict__ xUb)
{
  int idx = blockIdx.x * 256 + threadIdx.x;   // 512 * 2048
  int c = idx >> 11, n = idx & 2047;
  const float* ce = char_emb + (size_t)c * ECD;
  const float* wr = Wih_c + (size_t)n * ECD;
  float acc = bih_c[n] + bhh_c[n];
  for (int k = 0; k < ECD; k += 4) {
    float4 a = *(const float4*)(ce + k);
    float4 b = *(const float4*)(wr + k);
    acc += a.x*b.x + a.y*b.y + a.z*b.z + a.w*b.w;
  }
  xUb[idx] = f2bf(acc);
}

// ---------------- prep: h0 = prefix_emb[feat_seq] (bf16), c0 = 0 (bf16)
__global__ void prep_h0c0_k(const float* __restrict__ prefix_emb,
                            const int* __restrict__ feat_seq,
                            unsigned short* __restrict__ h0,
                            unsigned short* __restrict__ c0)
{
  int idx = blockIdx.x * 256 + threadIdx.x;  // 4096*512
  int s = idx >> 9, j = idx & 511;
  h0[idx] = f2bf(prefix_emb[(size_t)feat_seq[s] * HD + j]);
  c0[idx] = 0;
}

// ---------------- prep v4: quantize Whh_{f,b} rows to int8 with per-row scale.
// Wq layout: uint4 index = dir*16384 + q*1024 + row  (q = 0..15 covers k=16q..16q+15)
// u32 word m of a row covers k=4m..4m+3, byte j = k=4m+j. scales[dir][row] = max/16129.
__global__ void prep_scanw4_k(const float* __restrict__ Whh_f,
                              const float* __restrict__ Whh_b,
                              const float* __restrict__ bih_f,
                              const float* __restrict__ bhh_f,
                              const float* __restrict__ bih_b,
                              const float* __restrict__ bhh_b,
                              uint4* __restrict__ Wq,
                              float* __restrict__ scales,
                              float* __restrict__ biasbuf,
                              int* __restrict__ diag)
{
  int idx = blockIdx.x * 256 + threadIdx.x;   // 2048 threads: (dir, row)
  int row = idx & 1023;
  int dir = idx >> 10;
  const float* W = (dir ? Whh_b : Whh_f) + (size_t)row * HHD;
  float mx = 0.f;
  for (int k = 0; k < HHD; k += 4) {
    float4 w = *(const float4*)(W + k);
    mx = fmaxf(mx, fmaxf(fmaxf(fabsf(w.x), fabsf(w.y)), fmaxf(fabsf(w.z), fabsf(w.w))));
  }
  float qs = (mx > 0.f) ? (127.f / mx) : 0.f;
  scales[dir * 1024 + row] = mx / 16129.f;    // mx/(127*127)
  for (int q = 0; q < 16; ++q) {
    unsigned int wd[4];
#pragma unroll
    for (int c = 0; c < 4; ++c) {
      int k = q * 16 + c * 4;
      float4 w = *(const float4*)(W + k);
      unsigned int b0 = (unsigned int)((int)rintf(w.x * qs)) & 255u;
      unsigned int b1 = (unsigned int)((int)rintf(w.y * qs)) & 255u;
      unsigned int b2 = (unsigned int)((int)rintf(w.z * qs)) & 255u;
      unsigned int b3 = (unsigned int)((int)rintf(w.w * qs)) & 255u;
      wd[c] = b0 | (b1 << 8) | (b2 << 16) | (b3 << 24);
    }
    uint4 v; v.x = wd[0]; v.y = wd[1]; v.z = wd[2]; v.w = wd[3];
    Wq[dir * 16384 + q * 1024 + row] = v;
  }
  const float* bi = dir ? bih_b : bih_f;
  const float* bh = dir ? bhh_b : bhh_f;
  biasbuf[dir * 1024 + row] = bi[row] + bh[row];
  if (idx == 0) diag[0] = 0;
}

// ---------------- fused char-step: gates = h_in @ Whh_c^T (MFMA), then LSTM cell epilogue
__global__ __launch_bounds__(256) void gemm_char_k(
    const unsigned short* __restrict__ hin,   // [4096,512] bf16
    const float* __restrict__ Whh,            // [2048,512] f32
    const unsigned short* __restrict__ xUb,   // [512,2048] bf16
    const int* __restrict__ chars,
    const int* __restrict__ lens,
    int t,
    unsigned short* __restrict__ hout,        // [4096,512] bf16
    unsigned short* __restrict__ cb,          // [4096,512] bf16 (in/out)
    int* __restrict__ diag)
{
  __shared__ __align__(16) unsigned short As[128 * 32];
  __shared__ __align__(16) unsigned short Bs[128 * 32];
  __shared__ __align__(16) unsigned short gates[128 * 136];
  const int tid = threadIdx.x;
  const int m0 = blockIdx.y * 128;
  const int n0h = blockIdx.x * 32;            // base h-column of this tile
  const int wave = tid >> 6;
  const int lane = tid & 63;
  const int wm = (wave >> 1) * 64;
  const int wn = (wave & 1) * 64;
  float4v z = {0.f, 0.f, 0.f, 0.f};
  float4v acc[4][4];
#pragma unroll
  for (int i = 0; i < 4; ++i)
#pragma unroll
    for (int j = 0; j < 4; ++j) acc[i][j] = z;

  for (int k0 = 0; k0 < 512; k0 += 32) {
    __syncthreads();
#pragma unroll
    for (int i = 0; i < 2; ++i) {
      int chunk = tid * 2 + i;           // 0..511
      int row = chunk >> 2;              // 0..127
      int k8 = (chunk & 3) * 8;
      int4 av = *(const int4*)(hin + (size_t)(m0 + row) * 512 + k0 + k8);
      *(int4*)(As + row * 32 + k8) = av;
      int br = (row >> 5) * 512 + n0h + (row & 31);
      *(int4*)(Bs + row * 32 + k8) = cvt8(Whh + (size_t)br * 512 + k0 + k8);
    }
    __syncthreads();
    short8 af[4], bfr[4];
    const int kq = (lane >> 4) * 8;
#pragma unroll
    for (int i = 0; i < 4; ++i) {
      af[i]  = *(const short8*)(As + (wm + i * 16 + (lane & 15)) * 32 + kq);
      bfr[i] = *(const short8*)(Bs + (wn + i * 16 + (lane & 15)) * 32 + kq);
    }
#pragma unroll
    for (int i = 0; i < 4; ++i)
#pragma unroll
      for (int j = 0; j < 4; ++j)
        acc[i][j] = __builtin_amdgcn_mfma_f32_16x16x32_bf16(af[i], bfr[j], acc[i][j], 0, 0, 0);
  }
  __syncthreads();
#pragma unroll
  for (int i = 0; i < 4; ++i)
#pragma unroll
    for (int j = 0; j < 4; ++j)
#pragma unroll
      for (int r = 0; r < 4; ++r) {
        int row = wm + i * 16 + (lane >> 4) * 4 + r;
        int col = wn + j * 16 + (lane & 15);
        gates[row * 136 + col] = f2bf(acc[i][j][r]);
      }
  __syncthreads();
#pragma unroll
  for (int e = 0; e < 16; ++e) {
    int idx = e * 256 + tid;
    int r = idx >> 5, hc = idx & 31;
    int s = m0 + r;
    int col = n0h + hc;
    if (t < lens[s]) {
      int cid = chars[s * LL + t];
      size_t xb = (size_t)cid * 2048 + col;
      float gi = bf2f(gates[r * 136 + hc])      + bf2f(xUb[xb]);
      float gf = bf2f(gates[r * 136 + 32 + hc]) + bf2f(xUb[xb + 512]);
      float gg = bf2f(gates[r * 136 + 64 + hc]) + bf2f(xUb[xb + 1024]);
      float go = bf2f(gates[r * 136 + 96 + hc]) + bf2f(xUb[xb + 1536]);
      if (badf(gi + gf + gg + go)) atomicOr(diag, 1);
      float cc = sigf(gf) * bf2f(cb[(size_t)s * 512 + col]) + sigf(gi) * tanh_f(gg);
      cb[(size_t)s * 512 + col] = f2bf(cc);
      hout[(size_t)s * 512 + col] = f2bf(sigf(go) * tanh_f(cc));
    } else {
      hout[(size_t)s * 512 + col] = hin[(size_t)s * 512 + col];
    }
  }
}

// ---------------- P GEMM: P[M=4096, N=1024](bf16) = [word_emb[wseq] f32 | h bf16] @ Wih^T(f32)
__global__ __launch_bounds__(256) void gemm_gather_nt_k(
    const float* __restrict__ wemb,
    const int* __restrict__ wseq,
    const unsigned short* __restrict__ hbuf,
    const float* __restrict__ B,              // [1024,1024] f32
    unsigned short* __restrict__ P)           // [4096,1024] bf16
{
  __shared__ __align__(16) unsigned short As[128 * 32];
  __shared__ __align__(16) unsigned short Bs[128 * 32];
  const int tid = threadIdx.x;
  const int m0 = blockIdx.y * 128;
  const int n0 = blockIdx.x * 128;
  const int wave = tid >> 6;
  const int lane = tid & 63;
  const int wm = (wave >> 1) * 64;
  const int wn = (wave & 1) * 64;
  float4v z = {0.f, 0.f, 0.f, 0.f};
  float4v acc[4][4];
#pragma unroll
  for (int i = 0; i < 4; ++i)
#pragma unroll
    for (int j = 0; j < 4; ++j) acc[i][j] = z;

  for (int k0 = 0; k0 < 1024; k0 += 32) {
    __syncthreads();
#pragma unroll
    for (int i = 0; i < 2; ++i) {
      int chunk = tid * 2 + i;
      int row = chunk >> 2;
      int k8 = (chunk & 3) * 8;
      int arow = m0 + row;
      int acol = k0 + k8;
      if (acol < 512) {
        *(int4*)(As + row * 32 + k8) = cvt8(wemb + (size_t)wseq[arow] * 512 + acol);
      } else {
        int4 av = *(const int4*)(hbuf + (size_t)arow * 512 + (acol - 512));
        *(int4*)(As + row * 32 + k8) = av;
      }
      *(int4*)(Bs + row * 32 + k8) = cvt8(B + (size_t)(n0 + row) * 1024 + k0 + k8);
    }
    __syncthreads();
    short8 af[4], bfr[4];
    const int kq = (lane >> 4) * 8;
#pragma unroll
    for (int i = 0; i < 4; ++i) {
      af[i]  = *(const short8*)(As + (wm + i * 16 + (lane & 15)) * 32 + kq);
      bfr[i] = *(const short8*)(Bs + (wn + i * 16 + (lane & 15)) * 32 + kq);
    }
#pragma unroll
    for (int i = 0; i < 4; ++i)
#pragma unroll
      for (int j = 0; j < 4; ++j)
        acc[i][j] = __builtin_amdgcn_mfma_f32_16x16x32_bf16(af[i], bfr[j], acc[i][j], 0, 0, 0);
  }
#pragma unroll
  for (int i = 0; i < 4; ++i)
#pragma unroll
    for (int j = 0; j < 4; ++j)
#pragma unroll
      for (int r = 0; r < 4; ++r) {
        int row = m0 + wm + i * 16 + (lane >> 4) * 4 + r;
        int col = n0 + wn + j * 16 + (lane & 15);
        P[(size_t)row * 1024 + col] = f2bf(acc[i][j][r]);
      }
}

// ---------------- scan v9: r7's proven residency (10 VGPR + 6 LDS chunks, VGPR=88,
// conflict-free) combined with r8's single-barrier pair-gate structure, minus r8's bugs:
// (a) weight regs stay at 80 (below the spill cliff r8 hit at 96);
// (b) LDS-resident chunks staged INDEXED BY TID (thread tid owns slots [q][tid] and
//     [q][512+tid]) -> unit-stride ds_read_b128, zero bank conflicts.
// Thread pair (2u,2u+1) owns unit u: even computes rows (i: u, g: 512+u), odd
// (f: 256+u, o: 768+u). Two shfl_xor(1) deliver all 4 gates; cell thread-local on all
// 8 waves; h int8-packed double-buffered; ONE barrier/step.
__global__ __launch_bounds__(512) void scan9_k(
    const unsigned short* __restrict__ P_f,   // [4096,1024] bf16
    const unsigned short* __restrict__ P_b,
    const uint4* __restrict__ Wq,             // [2][16][1024] uint4 int8-packed
    const float* __restrict__ scales,         // [2][1024] f32
    const float* __restrict__ biasbuf,        // [2][1024] f32
    unsigned short* __restrict__ out_f,       // [4096,256] bf16
    unsigned short* __restrict__ out_b,
    int* __restrict__ diag, int dirsel)
{
  const int dir = (dirsel < 0) ? (int)blockIdx.x : dirsel;
  const int tid = threadIdx.x;
  const int u   = tid >> 1;                 // hidden unit 0..255
  const int odd = tid & 1;
  const int rA  = odd * 256 + u;            // even: gate i row; odd: gate f row
  const int rB  = rA + 512;                 // even: gate g row; odd: gate o row

  __shared__ __align__(16) uint4 ldsW[6 * 1024];          // 96 KB: chunks q=10..15, tid-indexed
  __shared__ __align__(16) unsigned int hq[2][64];        // int8-packed h, double-buffered

  const uint4* wp = Wq + (size_t)dir * 16384;
  uint4 wA[10], wB[10];
#pragma unroll
  for (int q = 0; q < 10; ++q) {
    wA[q] = wp[q * 1024 + rA];
    wB[q] = wp[q * 1024 + rB];
  }
  // stage chunks q=10..15 indexed by TID (slot tid holds row rA(tid); slot 512+tid holds rB(tid))
#pragma unroll
  for (int q = 10; q < 16; ++q) {
    ldsW[(q - 10) * 1024 + tid]       = wp[q * 1024 + rA];
    ldsW[(q - 10) * 1024 + 512 + tid] = wp[q * 1024 + rB];
  }
  const float sA = scales[dir * 1024 + rA];
  const float sB = scales[dir * 1024 + rB];
  const float bA = biasbuf[dir * 1024 + rA];
  const float bB = biasbuf[dir * 1024 + rB];
  const unsigned short* P = dir ? P_b : P_f;
  unsigned short* out = dir ? out_b : out_f;

  if (tid < 64) hq[0][tid] = 0u;
  float c_reg = 0.f;
  __syncthreads();

  // P prefetch for t=0
  const int srow0 = dir ? 4095 : 0;
  float pA = bf2f(P[(size_t)srow0 * 1024 + rA]);
  float pB = bf2f(P[(size_t)srow0 * 1024 + rB]);

  for (int t = 0; t < 4096; ++t) {
    const int srow = dir ? (4095 - t) : t;
    const int nrow = dir ? ((4094 - t) & 4095) : ((t + 1) & 4095);
    float npA = bf2f(P[(size_t)nrow * 1024 + rA]);
    float npB = bf2f(P[(size_t)nrow * 1024 + rB]);

    int accA = 0, accB = 0;
    const uint4* h4 = (const uint4*)&hq[t & 1][0];   // 16 broadcast uint4 (64 h-words)
#pragma unroll
    for (int q = 0; q < 10; ++q) {
      uint4 hv = h4[q];
      accA = dot4i8(wA[q].x, hv.x, accA);
      accA = dot4i8(wA[q].y, hv.y, accA);
      accA = dot4i8(wA[q].z, hv.z, accA);
      accA = dot4i8(wA[q].w, hv.w, accA);
      accB = dot4i8(wB[q].x, hv.x, accB);
      accB = dot4i8(wB[q].y, hv.y, accB);
      accB = dot4i8(wB[q].z, hv.z, accB);
      accB = dot4i8(wB[q].w, hv.w, accB);
    }
#pragma unroll
    for (int q = 10; q < 16; ++q) {
      uint4 hv = h4[q];
      uint4 wa = ldsW[(q - 10) * 1024 + tid];
      uint4 wb = ldsW[(q - 10) * 1024 + 512 + tid];
      accA = dot4i8(wa.x, hv.x, accA);
      accA = dot4i8(wa.y, hv.y, accA);
      accA = dot4i8(wa.z, hv.z, accA);
      accA = dot4i8(wa.w, hv.w, accA);
      accB = dot4i8(wb.x, hv.x, accB);
      accB = dot4i8(wb.y, hv.y, accB);
      accB = dot4i8(wb.z, hv.z, accB);
      accB = dot4i8(wb.w, hv.w, accB);
    }
    float gA = (float)accA * sA + bA + pA;
    float gB = (float)accB * sB + bB + pB;
    // pairwise gate exchange: even holds (i,g), odd holds (f,o)
    float xA = __shfl_xor(gA, 1);
    float xB = __shfl_xor(gB, 1);
    float gi = odd ? xA : gA;
    float gf = odd ? gA : xA;
    float gg = odd ? xB : gB;
    float go = odd ? gB : xB;
    float cc = sigf(gf) * c_reg + sigf(gi) * tanh_f(gg);
    float hh = sigf(go) * tanh_f(cc);
    c_reg = cc;
    if (!odd) {
      if (badf(gi + gf + gg + go)) atomicOr(diag, 2);
      out[(size_t)srow * HHD + u] = f2bf(hh);
    }
    // quantize h to int8/127; pack 4 units (8 lanes) per u32 via OR-reduce shfl
    unsigned int v = ((unsigned int)((int)rintf(hh * 127.f)) & 255u) << ((u & 3) * 8);
    v |= __shfl_xor(v, 1);
    v |= __shfl_xor(v, 2);
    v |= __shfl_xor(v, 4);
    if ((tid & 7) == 0) hq[(t + 1) & 1][tid >> 3] = v;
    pA = npA; pB = npB;
    __syncthreads();            // hq[(t+1)&1] ready; hq[t&1] fully consumed
  }
}

// ---------------- heads: logits + log_softmax -> f32 out
__global__ __launch_bounds__(128) void head_k(
    const unsigned short* __restrict__ out_f, const unsigned short* __restrict__ out_b,
    const float* __restrict__ Wpos, const float* __restrict__ bpos,
    const float* __restrict__ Wner, const float* __restrict__ bner,
    float* __restrict__ dout, int* __restrict__ diag)
{
  const int s = blockIdx.x, tid = threadIdx.x;
  __shared__ __align__(16) float xv[512];
#pragma unroll
  for (int i = 0; i < 4; ++i) {
    int k = tid * 4 + i;
    xv[k] = (k < 256) ? bf2f(out_f[(size_t)s * 256 + k])
                      : bf2f(out_b[(size_t)s * 256 + (k - 256)]);
  }
  __syncthreads();
  float logit = 0.f;
  const int j = tid;
  if (j < 96) {
    const float* wr = (j < 64) ? (Wpos + (size_t)j * 512)
                               : (Wner + (size_t)(j - 64) * 512);
    float b = (j < 64) ? bpos[j] : bner[j - 64];
    float acc = 0.f;
    for (int k = 0; k < 512; k += 4) {
      float4 wv = *(const float4*)(wr + k);
      acc += xv[k] * wv.x + xv[k + 1] * wv.y + xv[k + 2] * wv.z + xv[k + 3] * wv.w;
    }
    logit = acc + b;
    if (badf(logit)) { atomicOr(diag, 4); logit = 0.f; }
  }
  if (j < 64) {
    float m = logit;
    for (int o = 32; o >= 1; o >>= 1) m = fmaxf(m, __shfl_xor(m, o));
    float e = __expf(logit - m), sum = e;
    for (int o = 32; o >= 1; o >>= 1) sum += __shfl_xor(sum, o);
    float v = logit - m - logf(sum);
    if (!(v > -1e30f && v < 1e30f)) v = -111.f;
    dout[(size_t)s * 64 + j] = v;
  } else if (j < 96) {
    float m = logit;
    for (int o = 16; o >= 1; o >>= 1) m = fmaxf(m, __shfl_xor(m, o, 32));
    float e = __expf(logit - m), sum = e;
    for (int o = 16; o >= 1; o >>= 1) sum += __shfl_xor(sum, o, 32);
    float v = logit - m - logf(sum);
    if (!(v > -1e30f && v < 1e30f)) v = -111.f;
    dout[262144 + (size_t)s * 32 + (j - 64)] = v;
  }
}

// ---------------- diagnostics (silent when healthy)
__global__ void diag_k(const float* __restrict__ ce,
                       int* __restrict__ diag,
                       float* __restrict__ dout)
{
  int cnt = 0;
  for (int i = 0; i < 64; ++i) {
    float x = ce[i];
    if (x == x && fabsf(x) < 100.f) cnt++;
  }
  if (cnt < 48) diag[0] |= 8;
  int d = diag[0];
  if (d) dout[0] = 1000.f + 100.f * (float)d;
}

__global__ void wssmall_k(float* __restrict__ dout, int mb)
{
  dout[0] = 10000.f + (float)mb;
}

extern "C" void kernel_launch(void* const* d_in, const int* in_sizes, int n_in,
                              void* d_out, int out_size, void* d_ws, size_t ws_size,
                              hipStream_t stream) {
  const int*   word_seq  = (const int*)d_in[0];
  const int*   chars     = (const int*)d_in[1];
  const int*   char_lens = (const int*)d_in[2];
  const int*   feat_seq  = (const int*)d_in[3];
  const float* char_emb  = (const float*)d_in[4];
  const float* word_emb  = (const float*)d_in[5];
  const float* prefix_emb= (const float*)d_in[6];
  const float* Wih_c     = (const float*)d_in[7];
  const float* Whh_c     = (const float*)d_in[8];
  const float* bih_c     = (const float*)d_in[9];
  const float* bhh_c     = (const float*)d_in[10];
  const float* Wih_f     = (const float*)d_in[11];
  const float* Whh_f     = (const float*)d_in[12];
  const float* bih_f     = (const float*)d_in[13];
  const float* bhh_f     = (const float*)d_in[14];
  const float* Wih_b     = (const float*)d_in[15];
  const float* Whh_b     = (const float*)d_in[16];
  const float* bih_b     = (const float*)d_in[17];
  const float* bhh_b     = (const float*)d_in[18];
  const float* Wpos      = (const float*)d_in[19];
  const float* bpos      = (const float*)d_in[20];
  const float* Wner      = (const float*)d_in[21];
  const float* bner      = (const float*)d_in[22];
  float* dout = (float*)d_out;

  const size_t MB = 1048576;
  char* ws = (char*)d_ws;
  // small region
  int*            diag   = (int*)(ws + 512);            // 512 B
  float*          bias2  = (float*)(ws + 8192);         // 8 KB
  float*          scales = (float*)(ws + 16384);        // 8 KB
  uint4*          Wq     = (uint4*)(ws + 65536);        // 512 KB int8-packed weights
  // big region (phase-overlapped)
  unsigned short* hA    = (unsigned short*)(ws + 2 * MB);   // 4 MB [4096,512] bf16
  unsigned short* hB    = (unsigned short*)(ws + 6 * MB);   // 4 MB
  unsigned short* xUb   = (unsigned short*)(ws + 10 * MB);  // 2 MB [512,2048] bf16
  unsigned short* cb    = (unsigned short*)(ws + 12 * MB);  // 4 MB [4096,512] bf16

  const size_t NEED_A2 = 22 * MB;  // P_f 6..14, P_b 14..22 (both scans in parallel)
  const size_t NEED_B  = 16 * MB;  // sequential dir scans, shared P buffer
  unsigned short* P_f;
  unsigned short* P_b;
  unsigned short* out_f;
  unsigned short* out_b;
  int layoutA;
  if (ws_size >= NEED_A2) {
    layoutA = 1;
    P_f   = (unsigned short*)(ws + 6 * MB);    // over dead hB/xUb
    P_b   = (unsigned short*)(ws + 14 * MB);   // over dead cb + fresh
    out_f = (unsigned short*)(ws + 2 * MB);    // over dead hA
    out_b = (unsigned short*)(ws + 4 * MB);
  } else if (ws_size >= NEED_B) {
    layoutA = 0;
    P_f   = (unsigned short*)(ws + 6 * MB);
    P_b   = (unsigned short*)(ws + 6 * MB);
    out_f = (unsigned short*)(ws + 14 * MB);
    out_b = (unsigned short*)(ws + 2 * MB);
  } else {
    wssmall_k<<<1, 1, 0, stream>>>(dout, (int)(ws_size >> 20));
    return;
  }

  prep_xu_k<<<(512 * 2048) / 256, 256, 0, stream>>>(char_emb, Wih_c, bih_c, bhh_c, xUb);
  prep_h0c0_k<<<(4096 * 512) / 256, 256, 0, stream>>>(prefix_emb, feat_seq, hA, cb);
  prep_scanw4_k<<<2048 / 256, 256, 0, stream>>>(
      Whh_f, Whh_b, bih_f, bhh_f, bih_b, bhh_b, Wq, scales, bias2, diag);

  unsigned short* hcur = hA;
  unsigned short* hnxt = hB;
  for (int t = 0; t < 16; ++t) {
    gemm_char_k<<<dim3(16, 32), 256, 0, stream>>>(
        hcur, Whh_c, xUb, chars, char_lens, t, hnxt, cb, diag);
    unsigned short* tmp = hcur; hcur = hnxt; hnxt = tmp;
  }
  // after 16 swaps, final char features are in hA (hcur == hA)

  if (layoutA) {
    gemm_gather_nt_k<<<dim3(8, 32), 256, 0, stream>>>(word_emb, word_seq, hcur, Wih_f, P_f);
    gemm_gather_nt_k<<<dim3(8, 32), 256, 0, stream>>>(word_emb, word_seq, hcur, Wih_b, P_b);
    scan9_k<<<2, 512, 0, stream>>>(P_f, P_b, Wq, scales, bias2, out_f, out_b, diag, -1);
  } else {
    gemm_gather_nt_k<<<dim3(8, 32), 256, 0, stream>>>(word_emb, word_seq, hcur, Wih_f, P_f);
    scan9_k<<<1, 512, 0, stream>>>(P_f, P_b, Wq, scales, bias2, out_f, out_b, diag, 0);
    gemm_gather_nt_k<<<dim3(8, 32), 256, 0, stream>>>(word_emb, word_seq, hcur, Wih_b, P_b);
    scan9_k<<<1, 512, 0, stream>>>(P_f, P_b, Wq, scales, bias2, out_f, out_b, diag, 1);
  }

  head_k<<<4096, 128, 0, stream>>>(out_f, out_b, Wpos, bpos, Wner, bner, dout, diag);

  diag_k<<<1, 1, 0, stream>>>(char_emb, diag, dout);
}

// Round 11
// 5415.886 us; speedup vs baseline: 1.2022x; 1.2022x over previous
//
#include <hip/hip_runtime.h>

#define SS 4096
#define LL 16
#define HD 512
#define ECD 128
#define HHD 256

typedef __attribute__((ext_vector_type(8))) short short8;
typedef __attribute__((ext_vector_type(4))) float float4v;

__device__ __forceinline__ float bf2f(unsigned short u){
  union { unsigned int i; float f; } v; v.i = ((unsigned int)u) << 16; return v.f;
}
__device__ __forceinline__ unsigned short f2bf(float f){
  union { float f; unsigned int i; } v; v.f = f;
  unsigned int u = v.i;
  unsigned int r = (u + 0x7fffu + ((u >> 16) & 1u)) >> 16;
  return (unsigned short)r;
}
__device__ __forceinline__ float sigf(float x){ return 1.f / (1.f + __expf(-x)); }
__device__ __forceinline__ float tanh_f(float x){
  float e = __expf(2.f * x);
  return 1.f - 2.f / (e + 1.f);
}
__device__ __forceinline__ bool badf(float x){ return !(fabsf(x) < 1e30f); }

// int8 dot4: a,b are 4 packed signed int8; returns c + sum(a_i*b_i)
__device__ __forceinline__ int dot4i8(unsigned int a, unsigned int b, int c){
#if __has_builtin(__builtin_amdgcn_sdot4)
  return __builtin_amdgcn_sdot4((int)a, (int)b, c, false);
#else
  int s = c;
  s += (int)(char)(a)       * (int)(char)(b);
  s += (int)(char)(a >> 8)  * (int)(char)(b >> 8);
  s += (int)(char)(a >> 16) * (int)(char)(b >> 16);
  s += (int)(char)(a >> 24) * (int)(char)(b >> 24);
  return s;
#endif
}

// pack 8 f32 -> 8 bf16 (as int4) for LDS staging
__device__ __forceinline__ int4 cvt8(const float* __restrict__ s){
  union { unsigned short u[8]; int4 v; } pk;
#pragma unroll
  for (int i = 0; i < 8; ++i) pk.u[i] = f2bf(s[i]);
  return pk.v;
}

// ---------------- prep: xUb[c][n] = char_emb[c].Wih_c[n] + bih_c[n] + bhh_c[n]  (bf16 out)
__global__ void prep_xu_k(const float* __restrict__ char_emb,
                          const float* __restrict__ Wih_c,
                          const float* __restrict__ bih_c,
                          const float* __restrict__ bhh_c,
                          unsigned short* __restrict__ xUb)
{
  int idx = blockIdx.x * 256 + threadIdx.x;   // 512 * 2048
  int c = idx >> 11, n = idx & 2047;
  const float* ce = char_emb + (size_t)c * ECD;
  const float* wr = Wih_c + (size_t)n * ECD;
  float acc = bih_c[n] + bhh_c[n];
  for (int k = 0; k < ECD; k += 4) {
    float4 a = *(const float4*)(ce + k);
    float4 b = *(const float4*)(wr + k);
    acc += a.x*b.x + a.y*b.y + a.z*b.z + a.w*b.w;
  }
  xUb[idx] = f2bf(acc);
}

// ---------------- prep: h0 = prefix_emb[feat_seq] (bf16), c0 = 0 (bf16)
__global__ void prep_h0c0_k(const float* __restrict__ prefix_emb,
                            const int* __restrict__ feat_seq,
                            unsigned short* __restrict__ h0,
                            unsigned short* __restrict__ c0)
{
  int idx = blockIdx.x * 256 + threadIdx.x;  // 4096*512
  int s = idx >> 9, j = idx & 511;
  h0[idx] = f2bf(prefix_emb[(size_t)feat_seq[s] * HD + j]);
  c0[idx] = 0;
}

// ---------------- prep v4: quantize Whh_{f,b} rows to int8 with per-row scale.
// Wq layout: uint4 index = dir*16384 + q*1024 + row  (q = 0..15 covers k=16q..16q+15)
// u32 word m of a row covers k=4m..4m+3, byte j = k=4m+j. scales[dir][row] = max/16129.
__global__ void prep_scanw4_k(const float* __restrict__ Whh_f,
                              const float* __restrict__ Whh_b,
                              const float* __restrict__ bih_f,
                              const float* __restrict__ bhh_f,
                              const float* __restrict__ bih_b,
                              const float* __restrict__ bhh_b,
                              uint4* __restrict__ Wq,
                              float* __restrict__ scales,
                              float* __restrict__ biasbuf,
                              int* __restrict__ diag)
{
  int idx = blockIdx.x * 256 + threadIdx.x;   // 2048 threads: (dir, row)
  int row = idx & 1023;
  int dir = idx >> 10;
  const float* W = (dir ? Whh_b : Whh_f) + (size_t)row * HHD;
  float mx = 0.f;
  for (int k = 0; k < HHD; k += 4) {
    float4 w = *(const float4*)(W + k);
    mx = fmaxf(mx, fmaxf(fmaxf(fabsf(w.x), fabsf(w.y)), fmaxf(fabsf(w.z), fabsf(w.w))));
  }
  float qs = (mx > 0.f) ? (127.f / mx) : 0.f;
  scales[dir * 1024 + row] = mx / 16129.f;    // mx/(127*127)
  for (int q = 0; q < 16; ++q) {
    unsigned int wd[4];
#pragma unroll
    for (int c = 0; c < 4; ++c) {
      int k = q * 16 + c * 4;
      float4 w = *(const float4*)(W + k);
      unsigned int b0 = (unsigned int)((int)rintf(w.x * qs)) & 255u;
      unsigned int b1 = (unsigned int)((int)rintf(w.y * qs)) & 255u;
      unsigned int b2 = (unsigned int)((int)rintf(w.z * qs)) & 255u;
      unsigned int b3 = (unsigned int)((int)rintf(w.w * qs)) & 255u;
      wd[c] = b0 | (b1 << 8) | (b2 << 16) | (b3 << 24);
    }
    uint4 v; v.x = wd[0]; v.y = wd[1]; v.z = wd[2]; v.w = wd[3];
    Wq[dir * 16384 + q * 1024 + row] = v;
  }
  const float* bi = dir ? bih_b : bih_f;
  const float* bh = dir ? bhh_b : bhh_f;
  biasbuf[dir * 1024 + row] = bi[row] + bh[row];
  if (idx == 0) diag[0] = 0;
}

// ---------------- fused char-step: gates = h_in @ Whh_c^T (MFMA), then LSTM cell epilogue
__global__ __launch_bounds__(256) void gemm_char_k(
    const unsigned short* __restrict__ hin,   // [4096,512] bf16
    const float* __restrict__ Whh,            // [2048,512] f32
    const unsigned short* __restrict__ xUb,   // [512,2048] bf16
    const int* __restrict__ chars,
    const int* __restrict__ lens,
    int t,
    unsigned short* __restrict__ hout,        // [4096,512] bf16
    unsigned short* __restrict__ cb,          // [4096,512] bf16 (in/out)
    int* __restrict__ diag)
{
  __shared__ __align__(16) unsigned short As[128 * 32];
  __shared__ __align__(16) unsigned short Bs[128 * 32];
  __shared__ __align__(16) unsigned short gates[128 * 136];
  const int tid = threadIdx.x;
  const int m0 = blockIdx.y * 128;
  const int n0h = blockIdx.x * 32;            // base h-column of this tile
  const int wave = tid >> 6;
  const int lane = tid & 63;
  const int wm = (wave >> 1) * 64;
  const int wn = (wave & 1) * 64;
  float4v z = {0.f, 0.f, 0.f, 0.f};
  float4v acc[4][4];
#pragma unroll
  for (int i = 0; i < 4; ++i)
#pragma unroll
    for (int j = 0; j < 4; ++j) acc[i][j] = z;

  for (int k0 = 0; k0 < 512; k0 += 32) {
    __syncthreads();
#pragma unroll
    for (int i = 0; i < 2; ++i) {
      int chunk = tid * 2 + i;           // 0..511
      int row = chunk >> 2;              // 0..127
      int k8 = (chunk & 3) * 8;
      int4 av = *(const int4*)(hin + (size_t)(m0 + row) * 512 + k0 + k8);
      *(int4*)(As + row * 32 + k8) = av;
      int br = (row >> 5) * 512 + n0h + (row & 31);
      *(int4*)(Bs + row * 32 + k8) = cvt8(Whh + (size_t)br * 512 + k0 + k8);
    }
    __syncthreads();
    short8 af[4], bfr[4];
    const int kq = (lane >> 4) * 8;
#pragma unroll
    for (int i = 0; i < 4; ++i) {
      af[i]  = *(const short8*)(As + (wm + i * 16 + (lane & 15)) * 32 + kq);
      bfr[i] = *(const short8*)(Bs + (wn + i * 16 + (lane & 15)) * 32 + kq);
    }
#pragma unroll
    for (int i = 0; i < 4; ++i)
#pragma unroll
      for (int j = 0; j < 4; ++j)
        acc[i][j] = __builtin_amdgcn_mfma_f32_16x16x32_bf16(af[i], bfr[j], acc[i][j], 0, 0, 0);
  }
  __syncthreads();
#pragma unroll
  for (int i = 0; i < 4; ++i)
#pragma unroll
    for (int j = 0; j < 4; ++j)
#pragma unroll
      for (int r = 0; r < 4; ++r) {
        int row = wm + i * 16 + (lane >> 4) * 4 + r;
        int col = wn + j * 16 + (lane & 15);
        gates[row * 136 + col] = f2bf(acc[i][j][r]);
      }
  __syncthreads();
#pragma unroll
  for (int e = 0; e < 16; ++e) {
    int idx = e * 256 + tid;
    int r = idx >> 5, hc = idx & 31;
    int s = m0 + r;
    int col = n0h + hc;
    if (t < lens[s]) {
      int cid = chars[s * LL + t];
      size_t xb = (size_t)cid * 2048 + col;
      float gi = bf2f(gates[r * 136 + hc])      + bf2f(xUb[xb]);
      float gf = bf2f(gates[r * 136 + 32 + hc]) + bf2f(xUb[xb + 512]);
      float gg = bf2f(gates[r * 136 + 64 + hc]) + bf2f(xUb[xb + 1024]);
      float go = bf2f(gates[r * 136 + 96 + hc]) + bf2f(xUb[xb + 1536]);
      if (badf(gi + gf + gg + go)) atomicOr(diag, 1);
      float cc = sigf(gf) * bf2f(cb[(size_t)s * 512 + col]) + sigf(gi) * tanh_f(gg);
      cb[(size_t)s * 512 + col] = f2bf(cc);
      hout[(size_t)s * 512 + col] = f2bf(sigf(go) * tanh_f(cc));
    } else {
      hout[(size_t)s * 512 + col] = hin[(size_t)s * 512 + col];
    }
  }
}

// ---------------- P GEMM: P[M=4096, N=1024](bf16) = [word_emb[wseq] f32 | h bf16] @ Wih^T(f32)
__global__ __launch_bounds__(256) void gemm_gather_nt_k(
    const float* __restrict__ wemb,
    const int* __restrict__ wseq,
    const unsigned short* __restrict__ hbuf,
    const float* __restrict__ B,              // [1024,1024] f32
    unsigned short* __restrict__ P)           // [4096,1024] bf16
{
  __shared__ __align__(16) unsigned short As[128 * 32];
  __shared__ __align__(16) unsigned short Bs[128 * 32];
  const int tid = threadIdx.x;
  const int m0 = blockIdx.y * 128;
  const int n0 = blockIdx.x * 128;
  const int wave = tid >> 6;
  const int lane = tid & 63;
  const int wm = (wave >> 1) * 64;
  const int wn = (wave & 1) * 64;
  float4v z = {0.f, 0.f, 0.f, 0.f};
  float4v acc[4][4];
#pragma unroll
  for (int i = 0; i < 4; ++i)
#pragma unroll
    for (int j = 0; j < 4; ++j) acc[i][j] = z;

  for (int k0 = 0; k0 < 1024; k0 += 32) {
    __syncthreads();
#pragma unroll
    for (int i = 0; i < 2; ++i) {
      int chunk = tid * 2 + i;
      int row = chunk >> 2;
      int k8 = (chunk & 3) * 8;
      int arow = m0 + row;
      int acol = k0 + k8;
      if (acol < 512) {
        *(int4*)(As + row * 32 + k8) = cvt8(wemb + (size_t)wseq[arow] * 512 + acol);
      } else {
        int4 av = *(const int4*)(hbuf + (size_t)arow * 512 + (acol - 512));
        *(int4*)(As + row * 32 + k8) = av;
      }
      *(int4*)(Bs + row * 32 + k8) = cvt8(B + (size_t)(n0 + row) * 1024 + k0 + k8);
    }
    __syncthreads();
    short8 af[4], bfr[4];
    const int kq = (lane >> 4) * 8;
#pragma unroll
    for (int i = 0; i < 4; ++i) {
      af[i]  = *(const short8*)(As + (wm + i * 16 + (lane & 15)) * 32 + kq);
      bfr[i] = *(const short8*)(Bs + (wn + i * 16 + (lane & 15)) * 32 + kq);
    }
#pragma unroll
    for (int i = 0; i < 4; ++i)
#pragma unroll
      for (int j = 0; j < 4; ++j)
        acc[i][j] = __builtin_amdgcn_mfma_f32_16x16x32_bf16(af[i], bfr[j], acc[i][j], 0, 0, 0);
  }
#pragma unroll
  for (int i = 0; i < 4; ++i)
#pragma unroll
    for (int j = 0; j < 4; ++j)
#pragma unroll
      for (int r = 0; r < 4; ++r) {
        int row = m0 + wm + i * 16 + (lane >> 4) * 4 + r;
        int col = n0 + wn + j * 16 + (lane & 15);
        P[(size_t)row * 1024 + col] = f2bf(acc[i][j][r]);
      }
}

// ---------------- scan v10: 1024 threads, ONE gate row per thread, FULL VGPR residency.
// Thread tid owns gate row tid (K=256 int8 = 16 uint4 = 64 VGPRs). 16 waves = 4/SIMD
// (reg cap 128; r7 proved 64 weight regs + working fits). ZERO strided LDS weight reads.
// Per step: 64 sdot4 + 16 broadcast h reads + g_lds[tid] write; cell on tid<256;
// identical int8 math to r7 (same Wq/scales/order -> bitwise-same results).
__global__ __launch_bounds__(1024) void scan10_k(
    const unsigned short* __restrict__ P_f,   // [4096,1024] bf16
    const unsigned short* __restrict__ P_b,
    const uint4* __restrict__ Wq,             // [2][16][1024] uint4 int8-packed
    const float* __restrict__ scales,         // [2][1024] f32
    const float* __restrict__ biasbuf,        // [2][1024] f32
    unsigned short* __restrict__ out_f,       // [4096,256] bf16
    unsigned short* __restrict__ out_b,
    int* __restrict__ diag, int dirsel)
{
  const int dir = (dirsel < 0) ? (int)blockIdx.x : dirsel;
  const int tid = threadIdx.x;                // gate row 0..1023

  __shared__ __align__(16) float g_lds[1024];
  __shared__ __align__(16) unsigned int hq[2][64];   // int8-packed h, double-buffered

  const uint4* wp = Wq + (size_t)dir * 16384;
  uint4 w[16];                                // 64 VGPRs: full row resident
#pragma unroll
  for (int q = 0; q < 16; ++q) w[q] = wp[q * 1024 + tid];

  const float sc = scales[dir * 1024 + tid];
  const float bs = biasbuf[dir * 1024 + tid];
  const unsigned short* P = dir ? P_b : P_f;
  unsigned short* out = dir ? out_b : out_f;

  if (tid < 64) hq[0][tid] = 0u;
  float c_reg = 0.f;
  __syncthreads();

  // P prefetch for t=0
  const int srow0 = dir ? 4095 : 0;
  float pv = bf2f(P[(size_t)srow0 * 1024 + tid]);

  for (int t = 0; t < 4096; ++t) {
    const int srow = dir ? (4095 - t) : t;
    const int nrow = dir ? ((4094 - t) & 4095) : ((t + 1) & 4095);
    float npv = bf2f(P[(size_t)nrow * 1024 + tid]);

    int acc = 0;
    const uint4* h4 = (const uint4*)&hq[t & 1][0];   // 16 broadcast uint4 (64 h-words)
#pragma unroll
    for (int q = 0; q < 16; ++q) {
      uint4 hv = h4[q];
      acc = dot4i8(w[q].x, hv.x, acc);
      acc = dot4i8(w[q].y, hv.y, acc);
      acc = dot4i8(w[q].z, hv.z, acc);
      acc = dot4i8(w[q].w, hv.w, acc);
    }
    g_lds[tid] = (float)acc * sc + bs + pv;
    __syncthreads();            // gates ready; hq[t&1] fully consumed

    if (tid < 256) {
      float gi = g_lds[tid];
      float gf = g_lds[256 + tid];
      float gg = g_lds[512 + tid];
      float go = g_lds[768 + tid];
      if (badf(gi + gf + gg + go)) atomicOr(diag, 2);
      float cc = sigf(gf) * c_reg + sigf(gi) * tanh_f(gg);
      float hh = sigf(go) * tanh_f(cc);
      c_reg = cc;
      out[(size_t)srow * HHD + tid] = f2bf(hh);
      // quantize h to int8/127 and pack 4 units per u32 via shfl within the 4-group
      unsigned int v = ((unsigned int)((int)rintf(hh * 127.f)) & 255u) << ((tid & 3) * 8);
      v |= __shfl_xor(v, 1);
      v |= __shfl_xor(v, 2);
      if ((tid & 3) == 0) hq[(t + 1) & 1][tid >> 2] = v;
    }
    pv = npv;
    __syncthreads();            // new hq buffer ready
  }
}

// ---------------- heads: logits + log_softmax -> f32 out
__global__ __launch_bounds__(128) void head_k(
    const unsigned short* __restrict__ out_f, const unsigned short* __restrict__ out_b,
    const float* __restrict__ Wpos, const float* __restrict__ bpos,
    const float* __restrict__ Wner, const float* __restrict__ bner,
    float* __restrict__ dout, int* __restrict__ diag)
{
  const int s = blockIdx.x, tid = threadIdx.x;
  __shared__ __align__(16) float xv[512];
#pragma unroll
  for (int i = 0; i < 4; ++i) {
    int k = tid * 4 + i;
    xv[k] = (k < 256) ? bf2f(out_f[(size_t)s * 256 + k])
                      : bf2f(out_b[(size_t)s * 256 + (k - 256)]);
  }
  __syncthreads();
  float logit = 0.f;
  const int j = tid;
  if (j < 96) {
    const float* wr = (j < 64) ? (Wpos + (size_t)j * 512)
                               : (Wner + (size_t)(j - 64) * 512);
    float b = (j < 64) ? bpos[j] : bner[j - 64];
    float acc = 0.f;
    for (int k = 0; k < 512; k += 4) {
      float4 wv = *(const float4*)(wr + k);
      acc += xv[k] * wv.x + xv[k + 1] * wv.y + xv[k + 2] * wv.z + xv[k + 3] * wv.w;
    }
    logit = acc + b;
    if (badf(logit)) { atomicOr(diag, 4); logit = 0.f; }
  }
  if (j < 64) {
    float m = logit;
    for (int o = 32; o >= 1; o >>= 1) m = fmaxf(m, __shfl_xor(m, o));
    float e = __expf(logit - m), sum = e;
    for (int o = 32; o >= 1; o >>= 1) sum += __shfl_xor(sum, o);
    float v = logit - m - logf(sum);
    if (!(v > -1e30f && v < 1e30f)) v = -111.f;
    dout[(size_t)s * 64 + j] = v;
  } else if (j < 96) {
    float m = logit;
    for (int o = 16; o >= 1; o >>= 1) m = fmaxf(m, __shfl_xor(m, o, 32));
    float e = __expf(logit - m), sum = e;
    for (int o = 16; o >= 1; o >>= 1) sum += __shfl_xor(sum, o, 32);
    float v = logit - m - logf(sum);
    if (!(v > -1e30f && v < 1e30f)) v = -111.f;
    dout[262144 + (size_t)s * 32 + (j - 64)] = v;
  }
}

// ---------------- diagnostics (silent when healthy)
__global__ void diag_k(const float* __restrict__ ce,
                       int* __restrict__ diag,
                       float* __restrict__ dout)
{
  int cnt = 0;
  for (int i = 0; i < 64; ++i) {
    float x = ce[i];
    if (x == x && fabsf(x) < 100.f) cnt++;
  }
  if (cnt < 48) diag[0] |= 8;
  int d = diag[0];
  if (d) dout[0] = 1000.f + 100.f * (float)d;
}

__global__ void wssmall_k(float* __restrict__ dout, int mb)
{
  dout[0] = 10000.f + (float)mb;
}

extern "C" void kernel_launch(void* const* d_in, const int* in_sizes, int n_in,
                              void* d_out, int out_size, void* d_ws, size_t ws_size,
                              hipStream_t stream) {
  const int*   word_seq  = (const int*)d_in[0];
  const int*   chars     = (const int*)d_in[1];
  const int*   char_lens = (const int*)d_in[2];
  const int*   feat_seq  = (const int*)d_in[3];
  const float* char_emb  = (const float*)d_in[4];
  const float* word_emb  = (const float*)d_in[5];
  const float* prefix_emb= (const float*)d_in[6];
  const float* Wih_c     = (const float*)d_in[7];
  const float* Whh_c     = (const float*)d_in[8];
  const float* bih_c     = (const float*)d_in[9];
  const float* bhh_c     = (const float*)d_in[10];
  const float* Wih_f     = (const float*)d_in[11];
  const float* Whh_f     = (const float*)d_in[12];
  const float* bih_f     = (const float*)d_in[13];
  const float* bhh_f     = (const float*)d_in[14];
  const float* Wih_b     = (const float*)d_in[15];
  const float* Whh_b     = (const float*)d_in[16];
  const float* bih_b     = (const float*)d_in[17];
  const float* bhh_b     = (const float*)d_in[18];
  const float* Wpos      = (const float*)d_in[19];
  const float* bpos      = (const float*)d_in[20];
  const float* Wner      = (const float*)d_in[21];
  const float* bner      = (const float*)d_in[22];
  float* dout = (float*)d_out;

  const size_t MB = 1048576;
  char* ws = (char*)d_ws;
  // small region
  int*            diag   = (int*)(ws + 512);            // 512 B
  float*          bias2  = (float*)(ws + 8192);         // 8 KB
  float*          scales = (float*)(ws + 16384);        // 8 KB
  uint4*          Wq     = (uint4*)(ws + 65536);        // 512 KB int8-packed weights
  // big region (phase-overlapped)
  unsigned short* hA    = (unsigned short*)(ws + 2 * MB);   // 4 MB [4096,512] bf16
  unsigned short* hB    = (unsigned short*)(ws + 6 * MB);   // 4 MB
  unsigned short* xUb   = (unsigned short*)(ws + 10 * MB);  // 2 MB [512,2048] bf16
  unsigned short* cb    = (unsigned short*)(ws + 12 * MB);  // 4 MB [4096,512] bf16

  const size_t NEED_A2 = 22 * MB;  // P_f 6..14, P_b 14..22 (both scans in parallel)
  const size_t NEED_B  = 16 * MB;  // sequential dir scans, shared P buffer
  unsigned short* P_f;
  unsigned short* P_b;
  unsigned short* out_f;
  unsigned short* out_b;
  int layoutA;
  if (ws_size >= NEED_A2) {
    layoutA = 1;
    P_f   = (unsigned short*)(ws + 6 * MB);    // over dead hB/xUb
    P_b   = (unsigned short*)(ws + 14 * MB);   // over dead cb + fresh
    out_f = (unsigned short*)(ws + 2 * MB);    // over dead hA
    out_b = (unsigned short*)(ws + 4 * MB);
  } else if (ws_size >= NEED_B) {
    layoutA = 0;
    P_f   = (unsigned short*)(ws + 6 * MB);
    P_b   = (unsigned short*)(ws + 6 * MB);
    out_f = (unsigned short*)(ws + 14 * MB);
    out_b = (unsigned short*)(ws + 2 * MB);
  } else {
    wssmall_k<<<1, 1, 0, stream>>>(dout, (int)(ws_size >> 20));
    return;
  }

  prep_xu_k<<<(512 * 2048) / 256, 256, 0, stream>>>(char_emb, Wih_c, bih_c, bhh_c, xUb);
  prep_h0c0_k<<<(4096 * 512) / 256, 256, 0, stream>>>(prefix_emb, feat_seq, hA, cb);
  prep_scanw4_k<<<2048 / 256, 256, 0, stream>>>(
      Whh_f, Whh_b, bih_f, bhh_f, bih_b, bhh_b, Wq, scales, bias2, diag);

  unsigned short* hcur = hA;
  unsigned short* hnxt = hB;
  for (int t = 0; t < 16; ++t) {
    gemm_char_k<<<dim3(16, 32), 256, 0, stream>>>(
        hcur, Whh_c, xUb, chars, char_lens, t, hnxt, cb, diag);
    unsigned short* tmp = hcur; hcur = hnxt; hnxt = tmp;
  }
  // after 16 swaps, final char features are in hA (hcur == hA)

  if (layoutA) {
    gemm_gather_nt_k<<<dim3(8, 32), 256, 0, stream>>>(word_emb, word_seq, hcur, Wih_f, P_f);
    gemm_gather_nt_k<<<dim3(8, 32), 256, 0, stream>>>(word_emb, word_seq, hcur, Wih_b, P_b);
    scan10_k<<<2, 1024, 0, stream>>>(P_f, P_b, Wq, scales, bias2, out_f, out_b, diag, -1);
  } else {
    gemm_gather_nt_k<<<dim3(8, 32), 256, 0, stream>>>(word_emb, word_seq, hcur, Wih_f, P_f);
    scan10_k<<<1, 1024, 0, stream>>>(P_f, P_b, Wq, scales, bias2, out_f, out_b, diag, 0);
    gemm_gather_nt_k<<<dim3(8, 32), 256, 0, stream>>>(word_emb, word_seq, hcur, Wih_b, P_b);
    scan10_k<<<1, 1024, 0, stream>>>(P_f, P_b, Wq, scales, bias2, out_f, out_b, diag, 1);
  }

  head_k<<<4096, 128, 0, stream>>>(out_f, out_b, Wpos, bpos, Wner, bner, dout, diag);

  diag_k<<<1, 1, 0, stream>>>(char_emb, diag, dout);
}

// Round 12
// 5393.732 us; speedup vs baseline: 1.2071x; 1.0041x over previous
//
#include <hip/hip_runtime.h>

#define SS 4096
#define LL 16
#define HD 512
#define ECD 128
#define HHD 256

typedef __attribute__((ext_vector_type(8))) short short8;
typedef __attribute__((ext_vector_type(4))) float float4v;

__device__ __forceinline__ float bf2f(unsigned short u){
  union { unsigned int i; float f; } v; v.i = ((unsigned int)u) << 16; return v.f;
}
__device__ __forceinline__ unsigned short f2bf(float f){
  union { float f; unsigned int i; } v; v.f = f;
  unsigned int u = v.i;
  unsigned int r = (u + 0x7fffu + ((u >> 16) & 1u)) >> 16;
  return (unsigned short)r;
}
__device__ __forceinline__ float sigf(float x){ return 1.f / (1.f + __expf(-x)); }
__device__ __forceinline__ float tanh_f(float x){
  float e = __expf(2.f * x);
  return 1.f - 2.f / (e + 1.f);
}
__device__ __forceinline__ bool badf(float x){ return !(fabsf(x) < 1e30f); }

// int8 dot4: a,b are 4 packed signed int8; returns c + sum(a_i*b_i)
__device__ __forceinline__ int dot4i8(unsigned int a, unsigned int b, int c){
#if __has_builtin(__builtin_amdgcn_sdot4)
  return __builtin_amdgcn_sdot4((int)a, (int)b, c, false);
#else
  int s = c;
  s += (int)(char)(a)       * (int)(char)(b);
  s += (int)(char)(a >> 8)  * (int)(char)(b >> 8);
  s += (int)(char)(a >> 16) * (int)(char)(b >> 16);
  s += (int)(char)(a >> 24) * (int)(char)(b >> 24);
  return s;
#endif
}

// pack 8 f32 -> 8 bf16 (as int4) for LDS staging
__device__ __forceinline__ int4 cvt8(const float* __restrict__ s){
  union { unsigned short u[8]; int4 v; } pk;
#pragma unroll
  for (int i = 0; i < 8; ++i) pk.u[i] = f2bf(s[i]);
  return pk.v;
}

// ---------------- prep: xUb[c][n] = char_emb[c].Wih_c[n] + bih_c[n] + bhh_c[n]  (bf16 out)
__global__ void prep_xu_k(const float* __restrict__ char_emb,
                          const float* __restrict__ Wih_c,
                          const float* __restrict__ bih_c,
                          const float* __restrict__ bhh_c,
                          unsigned short* __restrict__ xUb)
{
  int idx = blockIdx.x * 256 + threadIdx.x;   // 512 * 2048
  int c = idx >> 11, n = idx & 2047;
  const float* ce = char_emb + (size_t)c * ECD;
  const float* wr = Wih_c + (size_t)n * ECD;
  float acc = bih_c[n] + bhh_c[n];
  for (int k = 0; k < ECD; k += 4) {
    float4 a = *(const float4*)(ce + k);
    float4 b = *(const float4*)(wr + k);
    acc += a.x*b.x + a.y*b.y + a.z*b.z + a.w*b.w;
  }
  xUb[idx] = f2bf(acc);
}

// ---------------- prep: h0 = prefix_emb[feat_seq] (bf16), c0 = 0 (bf16)
__global__ void prep_h0c0_k(const float* __restrict__ prefix_emb,
                            const int* __restrict__ feat_seq,
                            unsigned short* __restrict__ h0,
                            unsigned short* __restrict__ c0)
{
  int idx = blockIdx.x * 256 + threadIdx.x;  // 4096*512
  int s = idx >> 9, j = idx & 511;
  h0[idx] = f2bf(prefix_emb[(size_t)feat_seq[s] * HD + j]);
  c0[idx] = 0;
}

// ---------------- prep v4: quantize Whh_{f,b} rows to int8 with per-row scale.
// Wq layout: uint4 index = dir*16384 + q*1024 + row  (q = 0..15 covers k=16q..16q+15)
// u32 word m of a row covers k=4m..4m+3, byte j = k=4m+j. scales[dir][row] = max/16129.
__global__ void prep_scanw4_k(const float* __restrict__ Whh_f,
                              const float* __restrict__ Whh_b,
                              const float* __restrict__ bih_f,
                              const float* __restrict__ bhh_f,
                              const float* __restrict__ bih_b,
                              const float* __restrict__ bhh_b,
                              uint4* __restrict__ Wq,
                              float* __restrict__ scales,
                              float* __restrict__ biasbuf,
                              int* __restrict__ diag)
{
  int idx = blockIdx.x * 256 + threadIdx.x;   // 2048 threads: (dir, row)
  int row = idx & 1023;
  int dir = idx >> 10;
  const float* W = (dir ? Whh_b : Whh_f) + (size_t)row * HHD;
  float mx = 0.f;
  for (int k = 0; k < HHD; k += 4) {
    float4 w = *(const float4*)(W + k);
    mx = fmaxf(mx, fmaxf(fmaxf(fabsf(w.x), fabsf(w.y)), fmaxf(fabsf(w.z), fabsf(w.w))));
  }
  float qs = (mx > 0.f) ? (127.f / mx) : 0.f;
  scales[dir * 1024 + row] = mx / 16129.f;    // mx/(127*127)
  for (int q = 0; q < 16; ++q) {
    unsigned int wd[4];
#pragma unroll
    for (int c = 0; c < 4; ++c) {
      int k = q * 16 + c * 4;
      float4 w = *(const float4*)(W + k);
      unsigned int b0 = (unsigned int)((int)rintf(w.x * qs)) & 255u;
      unsigned int b1 = (unsigned int)((int)rintf(w.y * qs)) & 255u;
      unsigned int b2 = (unsigned int)((int)rintf(w.z * qs)) & 255u;
      unsigned int b3 = (unsigned int)((int)rintf(w.w * qs)) & 255u;
      wd[c] = b0 | (b1 << 8) | (b2 << 16) | (b3 << 24);
    }
    uint4 v; v.x = wd[0]; v.y = wd[1]; v.z = wd[2]; v.w = wd[3];
    Wq[dir * 16384 + q * 1024 + row] = v;
  }
  const float* bi = dir ? bih_b : bih_f;
  const float* bh = dir ? bhh_b : bhh_f;
  biasbuf[dir * 1024 + row] = bi[row] + bh[row];
  if (idx == 0) diag[0] = 0;
}

// ---------------- fused char-step: gates = h_in @ Whh_c^T (MFMA), then LSTM cell epilogue
__global__ __launch_bounds__(256) void gemm_char_k(
    const unsigned short* __restrict__ hin,   // [4096,512] bf16
    const float* __restrict__ Whh,            // [2048,512] f32
    const unsigned short* __restrict__ xUb,   // [512,2048] bf16
    const int* __restrict__ chars,
    const int* __restrict__ lens,
    int t,
    unsigned short* __restrict__ hout,        // [4096,512] bf16
    unsigned short* __restrict__ cb,          // [4096,512] bf16 (in/out)
    int* __restrict__ diag)
{
  __shared__ __align__(16) unsigned short As[128 * 32];
  __shared__ __align__(16) unsigned short Bs[128 * 32];
  __shared__ __align__(16) unsigned short gates[128 * 136];
  const int tid = threadIdx.x;
  const int m0 = blockIdx.y * 128;
  const int n0h = blockIdx.x * 32;            // base h-column of this tile
  const int wave = tid >> 6;
  const int lane = tid & 63;
  const int wm = (wave >> 1) * 64;
  const int wn = (wave & 1) * 64;
  float4v z = {0.f, 0.f, 0.f, 0.f};
  float4v acc[4][4];
#pragma unroll
  for (int i = 0; i < 4; ++i)
#pragma unroll
    for (int j = 0; j < 4; ++j) acc[i][j] = z;

  for (int k0 = 0; k0 < 512; k0 += 32) {
    __syncthreads();
#pragma unroll
    for (int i = 0; i < 2; ++i) {
      int chunk = tid * 2 + i;           // 0..511
      int row = chunk >> 2;              // 0..127
      int k8 = (chunk & 3) * 8;
      int4 av = *(const int4*)(hin + (size_t)(m0 + row) * 512 + k0 + k8);
      *(int4*)(As + row * 32 + k8) = av;
      int br = (row >> 5) * 512 + n0h + (row & 31);
      *(int4*)(Bs + row * 32 + k8) = cvt8(Whh + (size_t)br * 512 + k0 + k8);
    }
    __syncthreads();
    short8 af[4], bfr[4];
    const int kq = (lane >> 4) * 8;
#pragma unroll
    for (int i = 0; i < 4; ++i) {
      af[i]  = *(const short8*)(As + (wm + i * 16 + (lane & 15)) * 32 + kq);
      bfr[i] = *(const short8*)(Bs + (wn + i * 16 + (lane & 15)) * 32 + kq);
    }
#pragma unroll
    for (int i = 0; i < 4; ++i)
#pragma unroll
      for (int j = 0; j < 4; ++j)
        acc[i][j] = __builtin_amdgcn_mfma_f32_16x16x32_bf16(af[i], bfr[j], acc[i][j], 0, 0, 0);
  }
  __syncthreads();
#pragma unroll
  for (int i = 0; i < 4; ++i)
#pragma unroll
    for (int j = 0; j < 4; ++j)
#pragma unroll
      for (int r = 0; r < 4; ++r) {
        int row = wm + i * 16 + (lane >> 4) * 4 + r;
        int col = wn + j * 16 + (lane & 15);
        gates[row * 136 + col] = f2bf(acc[i][j][r]);
      }
  __syncthreads();
#pragma unroll
  for (int e = 0; e < 16; ++e) {
    int idx = e * 256 + tid;
    int r = idx >> 5, hc = idx & 31;
    int s = m0 + r;
    int col = n0h + hc;
    if (t < lens[s]) {
      int cid = chars[s * LL + t];
      size_t xb = (size_t)cid * 2048 + col;
      float gi = bf2f(gates[r * 136 + hc])      + bf2f(xUb[xb]);
      float gf = bf2f(gates[r * 136 + 32 + hc]) + bf2f(xUb[xb + 512]);
      float gg = bf2f(gates[r * 136 + 64 + hc]) + bf2f(xUb[xb + 1024]);
      float go = bf2f(gates[r * 136 + 96 + hc]) + bf2f(xUb[xb + 1536]);
      if (badf(gi + gf + gg + go)) atomicOr(diag, 1);
      float cc = sigf(gf) * bf2f(cb[(size_t)s * 512 + col]) + sigf(gi) * tanh_f(gg);
      cb[(size_t)s * 512 + col] = f2bf(cc);
      hout[(size_t)s * 512 + col] = f2bf(sigf(go) * tanh_f(cc));
    } else {
      hout[(size_t)s * 512 + col] = hin[(size_t)s * 512 + col];
    }
  }
}

// ---------------- P GEMM: P[M=4096, N=1024](bf16) = [word_emb[wseq] f32 | h bf16] @ Wih^T(f32)
__global__ __launch_bounds__(256) void gemm_gather_nt_k(
    const float* __restrict__ wemb,
    const int* __restrict__ wseq,
    const unsigned short* __restrict__ hbuf,
    const float* __restrict__ B,              // [1024,1024] f32
    unsigned short* __restrict__ P)           // [4096,1024] bf16
{
  __shared__ __align__(16) unsigned short As[128 * 32];
  __shared__ __align__(16) unsigned short Bs[128 * 32];
  const int tid = threadIdx.x;
  const int m0 = blockIdx.y * 128;
  const int n0 = blockIdx.x * 128;
  const int wave = tid >> 6;
  const int lane = tid & 63;
  const int wm = (wave >> 1) * 64;
  const int wn = (wave & 1) * 64;
  float4v z = {0.f, 0.f, 0.f, 0.f};
  float4v acc[4][4];
#pragma unroll
  for (int i = 0; i < 4; ++i)
#pragma unroll
    for (int j = 0; j < 4; ++j) acc[i][j] = z;

  for (int k0 = 0; k0 < 1024; k0 += 32) {
    __syncthreads();
#pragma unroll
    for (int i = 0; i < 2; ++i) {
      int chunk = tid * 2 + i;
      int row = chunk >> 2;
      int k8 = (chunk & 3) * 8;
      int arow = m0 + row;
      int acol = k0 + k8;
      if (acol < 512) {
        *(int4*)(As + row * 32 + k8) = cvt8(wemb + (size_t)wseq[arow] * 512 + acol);
      } else {
        int4 av = *(const int4*)(hbuf + (size_t)arow * 512 + (acol - 512));
        *(int4*)(As + row * 32 + k8) = av;
      }
      *(int4*)(Bs + row * 32 + k8) = cvt8(B + (size_t)(n0 + row) * 1024 + k0 + k8);
    }
    __syncthreads();
    short8 af[4], bfr[4];
    const int kq = (lane >> 4) * 8;
#pragma unroll
    for (int i = 0; i < 4; ++i) {
      af[i]  = *(const short8*)(As + (wm + i * 16 + (lane & 15)) * 32 + kq);
      bfr[i] = *(const short8*)(Bs + (wn + i * 16 + (lane & 15)) * 32 + kq);
    }
#pragma unroll
    for (int i = 0; i < 4; ++i)
#pragma unroll
      for (int j = 0; j < 4; ++j)
        acc[i][j] = __builtin_amdgcn_mfma_f32_16x16x32_bf16(af[i], bfr[j], acc[i][j], 0, 0, 0);
  }
#pragma unroll
  for (int i = 0; i < 4; ++i)
#pragma unroll
    for (int j = 0; j < 4; ++j)
#pragma unroll
      for (int r = 0; r < 4; ++r) {
        int row = m0 + wm + i * 16 + (lane >> 4) * 4 + r;
        int col = n0 + wn + j * 16 + (lane & 15);
        P[(size_t)row * 1024 + col] = f2bf(acc[i][j][r]);
      }
}

// ---------------- scan v11: 1024 threads, pair-split K. Thread pair (2p,2p+1):
// even thread handles K-chunks 0..7, odd chunks 8..15, each computing int partials
// for BOTH rows (2p, 2p+1). Two integer shfl_xor(1) reassemble exact full sums
// (int32 add is order-exact -> bitwise identical to v10). Row r0=2p weights held
// in 8 VGPR uint4 (32 regs, inside the allocator's observed comfort tier); row
// r1=2p+1 weights streamed from L2 with loop-invariant addresses. h-broadcast
// reads halved to 8/thread. Output row == tid for scale/bias/P/g_lds as in v10.
__global__ __launch_bounds__(1024) void scan11_k(
    const unsigned short* __restrict__ P_f,   // [4096,1024] bf16
    const unsigned short* __restrict__ P_b,
    const uint4* __restrict__ Wq,             // [2][16][1024] uint4 int8-packed
    const float* __restrict__ scales,         // [2][1024] f32
    const float* __restrict__ biasbuf,        // [2][1024] f32
    unsigned short* __restrict__ out_f,       // [4096,256] bf16
    unsigned short* __restrict__ out_b,
    int* __restrict__ diag, int dirsel)
{
  const int dir = (dirsel < 0) ? (int)blockIdx.x : dirsel;
  const int tid = threadIdx.x;                // output gate row 0..1023
  const int p   = tid >> 1;                   // pair index
  const int hh  = tid & 1;                    // K-half (0: chunks 0-7, 1: chunks 8-15)
  const int r0  = 2 * p;                      // partial-row 0
  const int r1  = 2 * p + 1;                  // partial-row 1 (streamed)
  const int qb  = hh * 8;                     // chunk base

  __shared__ __align__(16) float g_lds[1024];
  __shared__ __align__(16) unsigned int hq[2][64];   // int8-packed h, double-buffered

  const uint4* wp = Wq + (size_t)dir * 16384;
  uint4 w0[8];                                // row r0, chunks qb..qb+7 (32 VGPRs)
#pragma unroll
  for (int j = 0; j < 8; ++j) w0[j] = wp[(qb + j) * 1024 + r0];
  const uint4* w1p = wp + r1;                 // row r1 streamed: w1p[(qb+j)*1024]

  const float sc = scales[dir * 1024 + tid];
  const float bs = biasbuf[dir * 1024 + tid];
  const unsigned short* P = dir ? P_b : P_f;
  unsigned short* out = dir ? out_b : out_f;

  if (tid < 64) hq[0][tid] = 0u;
  float c_reg = 0.f;
  __syncthreads();

  // P prefetch for t=0
  const int srow0 = dir ? 4095 : 0;
  float pv = bf2f(P[(size_t)srow0 * 1024 + tid]);

  for (int t = 0; t < 4096; ++t) {
    const int srow = dir ? (4095 - t) : t;
    const int nrow = dir ? ((4094 - t) & 4095) : ((t + 1) & 4095);
    float npv = bf2f(P[(size_t)nrow * 1024 + tid]);

    int s0 = 0, s1 = 0;
    const uint4* h4 = (const uint4*)&hq[t & 1][0];
#pragma unroll
    for (int j = 0; j < 8; ++j) {
      uint4 hv = h4[qb + j];                  // broadcast: one read serves both rows
      uint4 a = w0[j];
      uint4 b = w1p[(size_t)(qb + j) * 1024]; // streamed (loop-invariant address)
      s0 = dot4i8(a.x, hv.x, s0);
      s0 = dot4i8(a.y, hv.y, s0);
      s0 = dot4i8(a.z, hv.z, s0);
      s0 = dot4i8(a.w, hv.w, s0);
      s1 = dot4i8(b.x, hv.x, s1);
      s1 = dot4i8(b.y, hv.y, s1);
      s1 = dot4i8(b.z, hv.z, s1);
      s1 = dot4i8(b.w, hv.w, s1);
    }
    // reassemble exact int sums across the pair: partner holds the other K-half
    int f0 = s0 + __shfl_xor(s0, 1);          // full sum for row 2p
    int f1 = s1 + __shfl_xor(s1, 1);          // full sum for row 2p+1
    int full = hh ? f1 : f0;                  // == full sum for row tid
    g_lds[tid] = (float)full * sc + bs + pv;
    __syncthreads();            // gates ready; hq[t&1] fully consumed

    if (tid < 256) {
      float gi = g_lds[tid];
      float gf = g_lds[256 + tid];
      float gg = g_lds[512 + tid];
      float go = g_lds[768 + tid];
      if (badf(gi + gf + gg + go)) atomicOr(diag, 2);
      float cc = sigf(gf) * c_reg + sigf(gi) * tanh_f(gg);
      float hh2 = sigf(go) * tanh_f(cc);
      c_reg = cc;
      out[(size_t)srow * HHD + tid] = f2bf(hh2);
      // quantize h to int8/127 and pack 4 units per u32 via shfl within the 4-group
      unsigned int v = ((unsigned int)((int)rintf(hh2 * 127.f)) & 255u) << ((tid & 3) * 8);
      v |= __shfl_xor(v, 1);
      v |= __shfl_xor(v, 2);
      if ((tid & 3) == 0) hq[(t + 1) & 1][tid >> 2] = v;
    }
    pv = npv;
    __syncthreads();            // new hq buffer ready
  }
}

// ---------------- heads: logits + log_softmax -> f32 out
__global__ __launch_bounds__(128) void head_k(
    const unsigned short* __restrict__ out_f, const unsigned short* __restrict__ out_b,
    const float* __restrict__ Wpos, const float* __restrict__ bpos,
    const float* __restrict__ Wner, const float* __restrict__ bner,
    float* __restrict__ dout, int* __restrict__ diag)
{
  const int s = blockIdx.x, tid = threadIdx.x;
  __shared__ __align__(16) float xv[512];
#pragma unroll
  for (int i = 0; i < 4; ++i) {
    int k = tid * 4 + i;
    xv[k] = (k < 256) ? bf2f(out_f[(size_t)s * 256 + k])
                      : bf2f(out_b[(size_t)s * 256 + (k - 256)]);
  }
  __syncthreads();
  float logit = 0.f;
  const int j = tid;
  if (j < 96) {
    const float* wr = (j < 64) ? (Wpos + (size_t)j * 512)
                               : (Wner + (size_t)(j - 64) * 512);
    float b = (j < 64) ? bpos[j] : bner[j - 64];
    float acc = 0.f;
    for (int k = 0; k < 512; k += 4) {
      float4 wv = *(const float4*)(wr + k);
      acc += xv[k] * wv.x + xv[k + 1] * wv.y + xv[k + 2] * wv.z + xv[k + 3] * wv.w;
    }
    logit = acc + b;
    if (badf(logit)) { atomicOr(diag, 4); logit = 0.f; }
  }
  if (j < 64) {
    float m = logit;
    for (int o = 32; o >= 1; o >>= 1) m = fmaxf(m, __shfl_xor(m, o));
    float e = __expf(logit - m), sum = e;
    for (int o = 32; o >= 1; o >>= 1) sum += __shfl_xor(sum, o);
    float v = logit - m - logf(sum);
    if (!(v > -1e30f && v < 1e30f)) v = -111.f;
    dout[(size_t)s * 64 + j] = v;
  } else if (j < 96) {
    float m = logit;
    for (int o = 16; o >= 1; o >>= 1) m = fmaxf(m, __shfl_xor(m, o, 32));
    float e = __expf(logit - m), sum = e;
    for (int o = 16; o >= 1; o >>= 1) sum += __shfl_xor(sum, o, 32);
    float v = logit - m - logf(sum);
    if (!(v > -1e30f && v < 1e30f)) v = -111.f;
    dout[262144 + (size_t)s * 32 + (j - 64)] = v;
  }
}

// ---------------- diagnostics (silent when healthy)
__global__ void diag_k(const float* __restrict__ ce,
                       int* __restrict__ diag,
                       float* __restrict__ dout)
{
  int cnt = 0;
  for (int i = 0; i < 64; ++i) {
    float x = ce[i];
    if (x == x && fabsf(x) < 100.f) cnt++;
  }
  if (cnt < 48) diag[0] |= 8;
  int d = diag[0];
  if (d) dout[0] = 1000.f + 100.f * (float)d;
}

__global__ void wssmall_k(float* __restrict__ dout, int mb)
{
  dout[0] = 10000.f + (float)mb;
}

extern "C" void kernel_launch(void* const* d_in, const int* in_sizes, int n_in,
                              void* d_out, int out_size, void* d_ws, size_t ws_size,
                              hipStream_t stream) {
  const int*   word_seq  = (const int*)d_in[0];
  const int*   chars     = (const int*)d_in[1];
  const int*   char_lens = (const int*)d_in[2];
  const int*   feat_seq  = (const int*)d_in[3];
  const float* char_emb  = (const float*)d_in[4];
  const float* word_emb  = (const float*)d_in[5];
  const float* prefix_emb= (const float*)d_in[6];
  const float* Wih_c     = (const float*)d_in[7];
  const float* Whh_c     = (const float*)d_in[8];
  const float* bih_c     = (const float*)d_in[9];
  const float* bhh_c     = (const float*)d_in[10];
  const float* Wih_f     = (const float*)d_in[11];
  const float* Whh_f     = (const float*)d_in[12];
  const float* bih_f     = (const float*)d_in[13];
  const float* bhh_f     = (const float*)d_in[14];
  const float* Wih_b     = (const float*)d_in[15];
  const float* Whh_b     = (const float*)d_in[16];
  const float* bih_b     = (const float*)d_in[17];
  const float* bhh_b     = (const float*)d_in[18];
  const float* Wpos      = (const float*)d_in[19];
  const float* bpos      = (const float*)d_in[20];
  const float* Wner      = (const float*)d_in[21];
  const float* bner      = (const float*)d_in[22];
  float* dout = (float*)d_out;

  const size_t MB = 1048576;
  char* ws = (char*)d_ws;
  // small region
  int*            diag   = (int*)(ws + 512);            // 512 B
  float*          bias2  = (float*)(ws + 8192);         // 8 KB
  float*          scales = (float*)(ws + 16384);        // 8 KB
  uint4*          Wq     = (uint4*)(ws + 65536);        // 512 KB int8-packed weights
  // big region (phase-overlapped)
  unsigned short* hA    = (unsigned short*)(ws + 2 * MB);   // 4 MB [4096,512] bf16
  unsigned short* hB    = (unsigned short*)(ws + 6 * MB);   // 4 MB
  unsigned short* xUb   = (unsigned short*)(ws + 10 * MB);  // 2 MB [512,2048] bf16
  unsigned short* cb    = (unsigned short*)(ws + 12 * MB);  // 4 MB [4096,512] bf16

  const size_t NEED_A2 = 22 * MB;  // P_f 6..14, P_b 14..22 (both scans in parallel)
  const size_t NEED_B  = 16 * MB;  // sequential dir scans, shared P buffer
  unsigned short* P_f;
  unsigned short* P_b;
  unsigned short* out_f;
  unsigned short* out_b;
  int layoutA;
  if (ws_size >= NEED_A2) {
    layoutA = 1;
    P_f   = (unsigned short*)(ws + 6 * MB);    // over dead hB/xUb
    P_b   = (unsigned short*)(ws + 14 * MB);   // over dead cb + fresh
    out_f = (unsigned short*)(ws + 2 * MB);    // over dead hA
    out_b = (unsigned short*)(ws + 4 * MB);
  } else if (ws_size >= NEED_B) {
    layoutA = 0;
    P_f   = (unsigned short*)(ws + 6 * MB);
    P_b   = (unsigned short*)(ws + 6 * MB);
    out_f = (unsigned short*)(ws + 14 * MB);
    out_b = (unsigned short*)(ws + 2 * MB);
  } else {
    wssmall_k<<<1, 1, 0, stream>>>(dout, (int)(ws_size >> 20));
    return;
  }

  prep_xu_k<<<(512 * 2048) / 256, 256, 0, stream>>>(char_emb, Wih_c, bih_c, bhh_c, xUb);
  prep_h0c0_k<<<(4096 * 512) / 256, 256, 0, stream>>>(prefix_emb, feat_seq, hA, cb);
  prep_scanw4_k<<<2048 / 256, 256, 0, stream>>>(
      Whh_f, Whh_b, bih_f, bhh_f, bih_b, bhh_b, Wq, scales, bias2, diag);

  unsigned short* hcur = hA;
  unsigned short* hnxt = hB;
  for (int t = 0; t < 16; ++t) {
    gemm_char_k<<<dim3(16, 32), 256, 0, stream>>>(
        hcur, Whh_c, xUb, chars, char_lens, t, hnxt, cb, diag);
    unsigned short* tmp = hcur; hcur = hnxt; hnxt = tmp;
  }
  // after 16 swaps, final char features are in hA (hcur == hA)

  if (layoutA) {
    gemm_gather_nt_k<<<dim3(8, 32), 256, 0, stream>>>(word_emb, word_seq, hcur, Wih_f, P_f);
    gemm_gather_nt_k<<<dim3(8, 32), 256, 0, stream>>>(word_emb, word_seq, hcur, Wih_b, P_b);
    scan11_k<<<2, 1024, 0, stream>>>(P_f, P_b, Wq, scales, bias2, out_f, out_b, diag, -1);
  } else {
    gemm_gather_nt_k<<<dim3(8, 32), 256, 0, stream>>>(word_emb, word_seq, hcur, Wih_f, P_f);
    scan11_k<<<1, 1024, 0, stream>>>(P_f, P_b, Wq, scales, bias2, out_f, out_b, diag, 0);
    gemm_gather_nt_k<<<dim3(8, 32), 256, 0, stream>>>(word_emb, word_seq, hcur, Wih_b, P_b);
    scan11_k<<<1, 1024, 0, stream>>>(P_f, P_b, Wq, scales, bias2, out_f, out_b, diag, 1);
  }

  head_k<<<4096, 128, 0, stream>>>(out_f, out_b, Wpos, bpos, Wner, bner, dout, diag);

  diag_k<<<1, 1, 0, stream>>>(char_emb, diag, dout);
}